// Round 1
// baseline (48.060 us; speedup 1.0000x reference)
//
#include <hip/hip_runtime.h>

// Problem constants (match reference)
constexpr int V    = 50265;  // vocab
constexpr int PADT = 1;      // pad token id
constexpr int BATCH = 512;
constexpr int SEQ   = 512;

// Kernel 1: zero the whole output (mandatory every call: harness poisons once
// and never re-poisons; most entries of the BM25 matrix are exactly 0).
// Also zero the global non-pad-token accumulator in workspace.
__global__ __launch_bounds__(256) void k_zero(float4* __restrict__ out, int n4,
                                              int* __restrict__ total) {
    int i = blockIdx.x * blockDim.x + threadIdx.x;
    if (i == 0) *total = 0;
    const float4 z = make_float4(0.f, 0.f, 0.f, 0.f);
    const int stride = gridDim.x * blockDim.x;
    for (int idx = i; idx < n4; idx += stride) out[idx] = z;
}

// Kernel 2: total = number of non-PAD tokens over the whole batch.
// Integer atomics -> exact & deterministic. avgdl = total / BATCH.
__global__ __launch_bounds__(256) void k_total(const int* __restrict__ ids,
                                               int* __restrict__ total) {
    int i = blockIdx.x * blockDim.x + threadIdx.x;  // grid sized exactly B*S
    int c = (ids[i] != PADT) ? 1 : 0;
    #pragma unroll
    for (int off = 32; off > 0; off >>= 1) c += __shfl_down(c, off, 64);
    __shared__ int sc[4];  // 256 threads = 4 waves
    const int lane = threadIdx.x & 63, w = threadIdx.x >> 6;
    if (lane == 0) sc[w] = c;
    __syncthreads();
    if (threadIdx.x == 0) atomicAdd(total, sc[0] + sc[1] + sc[2] + sc[3]);
}

// Kernel 3: one block per document row. Stage the row in LDS, recompute each
// token's count by scanning the row (broadcast LDS reads, conflict-free),
// then scatter the BM25 value. Duplicate tokens write bit-identical values
// (benign). PAD tokens skipped -> column 1 stays 0.
__global__ __launch_bounds__(512) void k_transform(const int* __restrict__ ids,
                                                   const int* __restrict__ total,
                                                   float* __restrict__ out) {
    __shared__ int row[SEQ];
    __shared__ int s_red[8];
    __shared__ float s_addend;

    const int b = blockIdx.x;
    const int t = threadIdx.x;
    row[t] = ids[b * SEQ + t];
    __syncthreads();

    const int id = row[t];

    // occurrences of my token in this row
    int c = 0;
    #pragma unroll 8
    for (int j = 0; j < SEQ; ++j) c += (row[j] == id) ? 1 : 0;

    // row's non-PAD length (block reduce)
    int np = (id != PADT) ? 1 : 0;
    #pragma unroll
    for (int off = 32; off > 0; off >>= 1) np += __shfl_down(np, off, 64);
    if ((t & 63) == 0) s_red[t >> 6] = np;
    __syncthreads();
    if (t == 0) {
        int dl = 0;
        #pragma unroll
        for (int j = 0; j < 8; ++j) dl += s_red[j];
        // d_avg = dl / (total/BATCH); dl*BATCH exact in fp32 (<= 2^18)
        float d_avg = (float)dl * (float)BATCH / (float)(*total);
        s_addend = 1.6f * (0.25f + 0.75f * d_avg);  // k*(1-b+b*d_avg), k=1.6 b=0.75
    }
    __syncthreads();

    if (id != PADT) {
        float fc = (float)c;
        out[(size_t)b * V + id] = fc * 2.6f / (fc + s_addend);  // c*(k+1)/(c+addend)
    }
}

extern "C" void kernel_launch(void* const* d_in, const int* in_sizes, int n_in,
                              void* d_out, int out_size, void* d_ws, size_t ws_size,
                              hipStream_t stream) {
    const int* ids = (const int*)d_in[0];   // input_ids, int32 [512*512]
    // d_in[1] = beta (unused by the reference computation)
    float* out = (float*)d_out;             // [512 * 50265] fp32
    int* total = (int*)d_ws;                // 4 bytes of scratch

    const int n4 = out_size / 4;            // 25,735,680 / 4 (divisible)
    k_zero<<<2048, 256, 0, stream>>>((float4*)out, n4, total);
    k_total<<<(BATCH * SEQ) / 256, 256, 0, stream>>>(ids, total);
    k_transform<<<BATCH, SEQ, 0, stream>>>(ids, total, out);
}

// Round 2
// 37.335 us; speedup vs baseline: 1.2872x; 1.2872x over previous
//
#include <hip/hip_runtime.h>

// Problem constants (match reference)
constexpr int V     = 50265;        // vocab size
constexpr int PADT  = 1;            // PAD token id
constexpr int BATCH = 512;
constexpr int SEQ   = 512;
constexpr int NPART = 128;          // partial-sum blocks
constexpr int HWORDS = (V + 1) / 2; // 25133 packed u32 words (2x u16 counts)

// Kernel 1: per-block partial counts of non-PAD tokens. Every partial slot is
// written every call (no zero-init dependency, deterministic).
__global__ __launch_bounds__(512) void k_partial(const int4* __restrict__ ids4,
                                                 int* __restrict__ partials) {
    const int t = threadIdx.x, b = blockIdx.x;
    const int4 v = ids4[b * 512 + t];   // 128 blk * 512 thr * 4 tok = 262144
    int c = (v.x != PADT) + (v.y != PADT) + (v.z != PADT) + (v.w != PADT);
    #pragma unroll
    for (int off = 32; off > 0; off >>= 1) c += __shfl_down(c, off, 64);
    __shared__ int sc[8];
    if ((t & 63) == 0) sc[t >> 6] = c;
    __syncthreads();
    if (t == 0) {
        int s = 0;
        #pragma unroll
        for (int j = 0; j < 8; ++j) s += sc[j];
        partials[b] = s;
    }
}

// Kernel 2: one block per document row. LDS histogram (16-bit packed counts),
// then ONE fully-coalesced streaming write of the whole output row (zeros
// included) -- no separate zero pass, no scattered RFO traffic.
__global__ __launch_bounds__(512) void k_fused(const int* __restrict__ ids,
                                               const int* __restrict__ partials,
                                               float* __restrict__ out) {
    __shared__ unsigned hist[HWORDS];   // 100.5 KB
    __shared__ int s_red[8];
    __shared__ float s_addend;

    const int b = blockIdx.x, t = threadIdx.x;

    // zero histogram
    for (int w = t; w < HWORDS; w += 512) hist[w] = 0u;

    const int id = ids[b * SEQ + t];
    __syncthreads();

    // scatter-add my token (packed 16-bit halves; counts <= 512 so no carry)
    int np = 0;
    if (id != PADT) {
        np = 1;
        atomicAdd(&hist[id >> 1], 1u << ((id & 1) * 16));
    }

    // row non-PAD length (block reduce)
    #pragma unroll
    for (int off = 32; off > 0; off >>= 1) np += __shfl_down(np, off, 64);
    if ((t & 63) == 0) s_red[t >> 6] = np;
    __syncthreads();

    if (t == 0) {
        int dl = 0;
        #pragma unroll
        for (int j = 0; j < 8; ++j) dl += s_red[j];
        int total = 0;                      // uniform -> scalar loads, L2-hot
        #pragma unroll
        for (int j = 0; j < NPART; ++j) total += partials[j];
        // d_avg = dl / (total/BATCH); dl*BATCH <= 2^18, exact in fp32
        float d_avg = (float)dl * (float)BATCH / (float)total;
        s_addend = 1.6f * (0.25f + 0.75f * d_avg);  // k*(1-b+b*d_avg)
    }
    __syncthreads();

    const float addend = s_addend;
    float* __restrict__ orow = out + (size_t)b * V;

    // stream the full row: lanes 0..63 hit 32 consecutive hist words (2 lanes
    // share a word -> broadcast, conflict-free); stores are 256B contiguous
    // per wave -> full-line HBM writes, no RFO.
    for (int v = t; v < V; v += 512) {
        const unsigned cw = hist[v >> 1];
        const float fc = (float)((cw >> ((v & 1) * 16)) & 0xffffu);
        orow[v] = (fc != 0.0f) ? fc * 2.6f / (fc + addend) : 0.0f;
    }
}

extern "C" void kernel_launch(void* const* d_in, const int* in_sizes, int n_in,
                              void* d_out, int out_size, void* d_ws, size_t ws_size,
                              hipStream_t stream) {
    const int* ids = (const int*)d_in[0];   // input_ids, int32 [512*512]
    // d_in[1] = beta (unused by the reference computation)
    float* out = (float*)d_out;             // [512 * 50265] fp32
    int* partials = (int*)d_ws;             // NPART ints of scratch

    k_partial<<<NPART, 512, 0, stream>>>((const int4*)ids, partials);
    k_fused<<<BATCH, 512, 0, stream>>>(ids, partials, out);
}

// Round 3
// 26.091 us; speedup vs baseline: 1.8420x; 1.4310x over previous
//
#include <hip/hip_runtime.h>

// Problem constants (match reference)
constexpr int V     = 50265;   // vocab size
constexpr int PADT  = 1;       // PAD token id
constexpr int BATCH = 512;
constexpr int SEQ   = 512;
constexpr int QS    = 12568;   // vocab quarter size (even, so packed words align)
constexpr int HQW   = QS / 2;  // 6284 packed u32 words (2x u16 counts) = 25.1 KB
constexpr int NPART = 64;      // one wave's worth of partials

// Kernel 1: 64 block-partials of the global non-PAD token count.
// Every slot written every call (no zero-init dependency, deterministic).
__global__ __launch_bounds__(512) void k_partial(const int4* __restrict__ ids4,
                                                 int* __restrict__ partials) {
    const int t = threadIdx.x, b = blockIdx.x;
    const int4 a = ids4[b * 1024 + t];          // 64 blk * 512 thr * 8 tok = 262144
    const int4 c4 = ids4[b * 1024 + 512 + t];
    int c = (a.x != PADT) + (a.y != PADT) + (a.z != PADT) + (a.w != PADT)
          + (c4.x != PADT) + (c4.y != PADT) + (c4.z != PADT) + (c4.w != PADT);
    #pragma unroll
    for (int off = 32; off > 0; off >>= 1) c += __shfl_down(c, off, 64);
    __shared__ int sc[8];
    if ((t & 63) == 0) sc[t >> 6] = c;
    __syncthreads();
    if (t == 0) {
        int s = 0;
        #pragma unroll
        for (int j = 0; j < 8; ++j) s += sc[j];
        partials[b] = s;
    }
}

// Kernel 2: one block per (row, vocab-quarter). 25.1 KB LDS histogram ->
// 4 blocks/CU (32 waves) so preambles overlap other blocks' store streams.
// Output written exactly once, fully coalesced (zeros included) -> no RFO.
__global__ __launch_bounds__(512) void k_fused(const int* __restrict__ ids,
                                               const int* __restrict__ partials,
                                               float* __restrict__ out) {
    __shared__ unsigned hist[HQW];
    __shared__ int s_red[8];
    __shared__ float s_addend;

    const int bq = blockIdx.x;
    const int b = bq >> 2, q = bq & 3;
    const int t = threadIdx.x;
    const int v0 = q * QS;
    const int vend = (v0 + QS < V) ? (v0 + QS) : V;

    // issue global loads early; latency hides under hist zeroing
    int pv = (t < NPART) ? partials[t] : 0;
    const int id = ids[b * SEQ + t];

    for (int w = t; w < HQW; w += 512) hist[w] = 0u;
    __syncthreads();

    // scatter my token if it lands in this quarter (16-bit packed; counts<=512)
    int np = (id != PADT) ? 1 : 0;
    if (id != PADT && id >= v0 && id < vend) {
        const int li = id - v0;
        atomicAdd(&hist[li >> 1], 1u << ((li & 1) * 16));
    }

    // full-row non-PAD length (redundant across the 4 quarter-blocks; cheap)
    #pragma unroll
    for (int off = 32; off > 0; off >>= 1) np += __shfl_down(np, off, 64);
    if ((t & 63) == 0) s_red[t >> 6] = np;
    __syncthreads();

    if (t < 64) {
        // wave-parallel global total (loads were issued at kernel entry)
        #pragma unroll
        for (int off = 32; off > 0; off >>= 1) pv += __shfl_down(pv, off, 64);
        if (t == 0) {
            int dl = 0;
            #pragma unroll
            for (int j = 0; j < 8; ++j) dl += s_red[j];
            // d_avg = dl / (total/BATCH); dl*BATCH <= 2^18, exact in fp32
            float d_avg = (float)dl * (float)BATCH / (float)pv;
            s_addend = 1.6f * (0.25f + 0.75f * d_avg);  // k*(1-b+b*d_avg)
        }
    }
    __syncthreads();

    const float addend = s_addend;
    float* __restrict__ orow = out + (size_t)b * V;

    // stream this quarter: consecutive lanes -> consecutive words (2 lanes
    // broadcast-share one hist word, conflict-free); 256B/wave stores.
    // fc==0 -> (0*2.6)*rcp(addend) == 0 exactly; rcp error ~1ulp << 3.4e-2.
    for (int v = v0 + t; v < vend; v += 512) {
        const int li = v - v0;
        const unsigned cw = hist[li >> 1];
        const float fc = (float)((cw >> ((li & 1) * 16)) & 0xffffu);
        orow[v] = (fc * 2.6f) * __builtin_amdgcn_rcpf(fc + addend);
    }
}

extern "C" void kernel_launch(void* const* d_in, const int* in_sizes, int n_in,
                              void* d_out, int out_size, void* d_ws, size_t ws_size,
                              hipStream_t stream) {
    const int* ids = (const int*)d_in[0];   // input_ids, int32 [512*512]
    // d_in[1] = beta (unused by the reference computation)
    float* out = (float*)d_out;             // [512 * 50265] fp32
    int* partials = (int*)d_ws;             // NPART ints of scratch

    k_partial<<<NPART, 512, 0, stream>>>((const int4*)ids, partials);
    k_fused<<<BATCH * 4, 512, 0, stream>>>(ids, partials, out);
}